// Round 1
// baseline (68.193 us; speedup 1.0000x reference)
//
#include <hip/hip_runtime.h>
#include <utility>

#define DEV __device__ __forceinline__

constexpr int NV = 16;
constexpr float STEP = 0.1f;
constexpr int MAX_ITER = 20;

// ---- compile-time for loop (needed so DPP ctrl / register indices are ICEs) ----
template <class F, int... Is>
DEV void sf_impl(F&& f, std::integer_sequence<int, Is...>) {
  (f(std::integral_constant<int, Is>{}), ...);
}
template <int N, class F>
DEV void static_for(F&& f) {
  sf_impl(f, std::make_integer_sequence<int, N>{});
}

// ---- broadcast lane Q within each quad via DPP quad_perm (pure VALU, no LDS) ----
template <int Q>
DEV float qbcast(float v) {
  int r = __builtin_amdgcn_update_dpp(0, __float_as_int(v), Q * 0x55, 0xF, 0xF, true);
  return __int_as_float(r);
}

// rcp + one Newton refinement: ~full f32 precision, ~3 VALU ops vs ~10 for precise div
DEV float rcp_nr(float x) {
  float r = __builtin_amdgcn_rcpf(x);
  return r * __builtin_fmaf(-x, r, 2.0f);
}

// One quad (4 lanes) per batch row. Lane l owns global variable rows {4l..4l+3}.
// Everything register-resident with static indexing; all cross-lane = DPP quad bcast.
__global__ __launch_bounds__(256, 1) void newton16(
    const float* __restrict__ y0, const float* __restrict__ xin,
    const float* __restrict__ Ain, float* __restrict__ out, int B) {
  const int tid = blockIdx.x * blockDim.x + threadIdx.x;
  const int g = tid >> 2;  // batch row
  const int l = tid & 3;   // lane within quad
  if (g >= B) return;

  // A rows for my 4 variables: 64 VGPRs, loaded once (L2/L3 broadcast)
  float Arow[4][16];
#pragma unroll
  for (int m = 0; m < 4; ++m) {
    const float4* ap = reinterpret_cast<const float4*>(Ain + (4 * l + m) * NV);
#pragma unroll
    for (int t = 0; t < 4; ++t) {
      float4 a = ap[t];
      Arow[m][4 * t + 0] = a.x;
      Arow[m][4 * t + 1] = a.y;
      Arow[m][4 * t + 2] = a.z;
      Arow[m][4 * t + 3] = a.w;
    }
  }

  float y[4], x[4];
  {
    float4 t = *reinterpret_cast<const float4*>(y0 + g * NV + 4 * l);
    y[0] = t.x; y[1] = t.y; y[2] = t.z; y[3] = t.w;
    float4 u = *reinterpret_cast<const float4*>(xin + g * NV + 4 * l);
    x[0] = u.x; x[1] = u.y; x[2] = u.z; x[3] = u.w;
  }

  // eqf[q] = (l==q) ? 1 : 0  -- lets diag-add / pivot masking be a single fma/mul
  float eqf[4];
#pragma unroll
  for (int q = 0; q < 4; ++q) eqf[q] = (l == q) ? 1.0f : 0.0f;

  for (int it = 0; it < MAX_ITER; ++it) {
    // local trig (args are O(1) rad -> hw v_sin/v_cos fine)
    float s[4], c[4];
#pragma unroll
    for (int m = 0; m < 4; ++m) {
      s[m] = __sinf(y[m]);
      c[m] = __cosf(y[m]);
    }

    // full sin/cos vectors via quad broadcast (32 DPP movs)
    float sf16[16], cf16[16];
    static_for<16>([&](auto JJ) {
      constexpr int j = JJ.value;
      sf16[j] = qbcast<(j >> 2)>(s[j & 3]);
      cf16[j] = qbcast<(j >> 2)>(c[j & 3]);
    });

    // b = -r = x - y^3 - A*sin(y)   (for my 4 rows)
    float b[4];
#pragma unroll
    for (int m = 0; m < 4; ++m) {
      float acc = x[m] - y[m] * y[m] * y[m];
#pragma unroll
      for (int j = 0; j < 16; ++j) acc = __builtin_fmaf(-Arow[m][j], sf16[j], acc);
      b[m] = acc;
    }

    // J rows: J[m][j] = A[m][j]*cos(y_j) + (4l+m==j)*3*y_m^2
    float Jm[4][16];
#pragma unroll
    for (int m = 0; m < 4; ++m) {
      float t3 = 3.0f * y[m] * y[m];
#pragma unroll
      for (int j = 0; j < 16; ++j) {
        float v = Arow[m][j] * cf16[j];
        if ((j & 3) == m) v = __builtin_fmaf(eqf[j >> 2], t3, v);  // static cond on (j,m)
        Jm[m][j] = v;
      }
    }

    // ---- unpivoted Gauss-Jordan, fully unrolled; pivot k owned by lane k>>2 slot k&3 ----
    float dg[4] = {1.0f, 1.0f, 1.0f, 1.0f};
    static_for<16>([&](auto KK) {
      constexpr int k = KK.value;
      constexpr int q = k >> 2, mk = k & 3;
      float pk = qbcast<q>(Jm[mk][k]);
      float bk = qbcast<q>(b[mk]);
      float inv = rcp_nr(pk);
      float f[4];
#pragma unroll
      for (int m = 0; m < 4; ++m) f[m] = Jm[m][k] * inv;
      f[mk] *= (1.0f - eqf[q]);          // owner lane keeps its pivot row
      dg[mk] = (l == q) ? pk : dg[mk];   // save my diagonal pivot
      static_for<16 - k - 1>([&](auto JJ) {
        constexpr int j = k + 1 + JJ.value;
        float rkj = qbcast<q>(Jm[mk][j]);
#pragma unroll
        for (int m = 0; m < 4; ++m) Jm[m][j] = __builtin_fmaf(-f[m], rkj, Jm[m][j]);
      });
#pragma unroll
      for (int m = 0; m < 4; ++m) b[m] = __builtin_fmaf(-f[m], bk, b[m]);
    });

    // delta = b / diag;  y += STEP*delta
#pragma unroll
    for (int m = 0; m < 4; ++m) {
      float d = b[m] * rcp_nr(dg[m]);
      y[m] = __builtin_fmaf(STEP, d, y[m]);
    }
  }

  float4 o;
  o.x = y[0]; o.y = y[1]; o.z = y[2]; o.w = y[3];
  *reinterpret_cast<float4*>(out + g * NV + 4 * l) = o;
}

extern "C" void kernel_launch(void* const* d_in, const int* in_sizes, int n_in,
                              void* d_out, int out_size, void* d_ws, size_t ws_size,
                              hipStream_t stream) {
  const float* y = (const float*)d_in[0];
  const float* x = (const float*)d_in[1];
  const float* A = (const float*)d_in[2];
  float* out = (float*)d_out;
  const int B = in_sizes[0] / NV;      // 32768
  const int threads = B * 4;           // one quad per batch row
  dim3 block(256);
  dim3 grid((threads + block.x - 1) / block.x);
  hipLaunchKernelGGL(newton16, grid, block, 0, stream, y, x, A, out, B);
}

// Round 2
// 66.017 us; speedup vs baseline: 1.0330x; 1.0330x over previous
//
#include <hip/hip_runtime.h>
#include <utility>

#define DEV __device__ __forceinline__

constexpr int NV = 16;
constexpr float STEP = 0.1f;
constexpr int MAX_ITER = 20;

// ---- compile-time for loop (DPP ctrl / register indices must be ICEs) ----
template <class F, int... Is>
DEV void sf_impl(F&& f, std::integer_sequence<int, Is...>) {
  (f(std::integral_constant<int, Is>{}), ...);
}
template <int N, class F>
DEV void static_for(F&& f) {
  sf_impl(f, std::make_integer_sequence<int, N>{});
}

// ---- broadcast lane Q within each quad via DPP quad_perm (pure VALU, no LDS) ----
// old operand = src (don't-care: all lanes written at masks 0xF + bound_ctrl),
// avoids the compiler materializing a v_mov 0 for `old`.
template <int Q>
DEV float qbcast(float v) {
  int iv = __float_as_int(v);
  int r = __builtin_amdgcn_update_dpp(iv, iv, Q * 0x55, 0xF, 0xF, true);
  return __int_as_float(r);
}

// v_rcp_f32 is ~1 ulp: plenty for a 0.1-damped Newton trajectory at 3e-2 tol.
DEV float rcp_fast(float x) { return __builtin_amdgcn_rcpf(x); }

// One quad (4 lanes) per batch row. Lane l owns global variable rows {4l..4l+3}.
// Everything register-resident with static indexing; all cross-lane = DPP quad bcast.
__global__ __attribute__((amdgpu_flat_work_group_size(256, 256),
                          amdgpu_waves_per_eu(1, 2)))  // occupancy is thread-limited to 2
void newton16(const float* __restrict__ y0, const float* __restrict__ xin,
              const float* __restrict__ Ain, float* __restrict__ out, int B) {
  const int tid = blockIdx.x * blockDim.x + threadIdx.x;
  const int g = tid >> 2;  // batch row
  const int l = tid & 3;   // lane within quad
  if (g >= B) return;

  // A rows for my 4 variables: 64 VGPRs, loaded once (must STAY resident)
  float Arow[4][16];
#pragma unroll
  for (int m = 0; m < 4; ++m) {
    const float4* ap = reinterpret_cast<const float4*>(Ain + (4 * l + m) * NV);
#pragma unroll
    for (int t = 0; t < 4; ++t) {
      float4 a = ap[t];
      Arow[m][4 * t + 0] = a.x;
      Arow[m][4 * t + 1] = a.y;
      Arow[m][4 * t + 2] = a.z;
      Arow[m][4 * t + 3] = a.w;
    }
  }

  float y[4], x[4];
  {
    float4 t = *reinterpret_cast<const float4*>(y0 + g * NV + 4 * l);
    y[0] = t.x; y[1] = t.y; y[2] = t.z; y[3] = t.w;
    float4 u = *reinterpret_cast<const float4*>(xin + g * NV + 4 * l);
    x[0] = u.x; x[1] = u.y; x[2] = u.z; x[3] = u.w;
  }

  // eqf[q] = (l==q) ? 1 : 0 ; neqf = 1 - eqf  (hoisted mask constants)
  float eqf[4], neqf[4];
#pragma unroll
  for (int q = 0; q < 4; ++q) {
    eqf[q] = (l == q) ? 1.0f : 0.0f;
    neqf[q] = 1.0f - eqf[q];
  }

#pragma unroll 1  // keep body ~1k instrs: full unroll would thrash I-cache
  for (int it = 0; it < MAX_ITER; ++it) {
    // local trig (args O(1) rad -> hw v_sin/v_cos fine)
    float s[4], c[4];
#pragma unroll
    for (int m = 0; m < 4; ++m) {
      s[m] = __sinf(y[m]);
      c[m] = __cosf(y[m]);
    }

    // full sin/cos vectors via quad broadcast (32 DPP movs)
    float sf16[16], cf16[16];
    static_for<16>([&](auto JJ) {
      constexpr int j = JJ.value;
      sf16[j] = qbcast<(j >> 2)>(s[j & 3]);
      cf16[j] = qbcast<(j >> 2)>(c[j & 3]);
    });

    // b = -r = x - y^3 - A*sin(y)   (for my 4 rows)
    float b[4];
#pragma unroll
    for (int m = 0; m < 4; ++m) {
      float acc = x[m] - y[m] * y[m] * y[m];
#pragma unroll
      for (int j = 0; j < 16; ++j) acc = __builtin_fmaf(-Arow[m][j], sf16[j], acc);
      b[m] = acc;
    }

    // J rows: J[m][j] = A[m][j]*cos(y_j) + (4l+m==j)*3*y_m^2
    float Jm[4][16];
#pragma unroll
    for (int m = 0; m < 4; ++m) {
      float t3 = 3.0f * y[m] * y[m];
#pragma unroll
      for (int j = 0; j < 16; ++j) {
        float v = Arow[m][j] * cf16[j];
        if ((j & 3) == m) v = __builtin_fmaf(eqf[j >> 2], t3, v);  // static cond on (j,m)
        Jm[m][j] = v;
      }
    }

    // ---- unpivoted Gauss-Jordan, fully unrolled; pivot k owned by lane k>>2 slot k&3 ----
    float dg[4] = {1.0f, 1.0f, 1.0f, 1.0f};
    static_for<16>([&](auto KK) {
      constexpr int k = KK.value;
      constexpr int q = k >> 2, mk = k & 3;
      float pk = qbcast<q>(Jm[mk][k]);
      float bk = qbcast<q>(b[mk]);
      float inv = rcp_fast(pk);
      float f[4];
#pragma unroll
      for (int m = 0; m < 4; ++m) f[m] = Jm[m][k] * inv;
      f[mk] *= neqf[q];                  // owner lane keeps its pivot row
      dg[mk] = (l == q) ? pk : dg[mk];   // save my diagonal pivot
      static_for<16 - k - 1>([&](auto JJ) {
        constexpr int j = k + 1 + JJ.value;
        float rkj = qbcast<q>(Jm[mk][j]);
#pragma unroll
        for (int m = 0; m < 4; ++m) Jm[m][j] = __builtin_fmaf(-f[m], rkj, Jm[m][j]);
      });
#pragma unroll
      for (int m = 0; m < 4; ++m) b[m] = __builtin_fmaf(-f[m], bk, b[m]);
    });

    // delta = b / diag;  y += STEP*delta
#pragma unroll
    for (int m = 0; m < 4; ++m) {
      float d = b[m] * rcp_fast(dg[m]);
      y[m] = __builtin_fmaf(STEP, d, y[m]);
    }
  }

  float4 o;
  o.x = y[0]; o.y = y[1]; o.z = y[2]; o.w = y[3];
  *reinterpret_cast<float4*>(out + g * NV + 4 * l) = o;
}

extern "C" void kernel_launch(void* const* d_in, const int* in_sizes, int n_in,
                              void* d_out, int out_size, void* d_ws, size_t ws_size,
                              hipStream_t stream) {
  const float* y = (const float*)d_in[0];
  const float* x = (const float*)d_in[1];
  const float* A = (const float*)d_in[2];
  float* out = (float*)d_out;
  const int B = in_sizes[0] / NV;      // 32768
  const int threads = B * 4;           // one quad per batch row
  dim3 block(256);
  dim3 grid((threads + block.x - 1) / block.x);
  hipLaunchKernelGGL(newton16, grid, block, 0, stream, y, x, A, out, B);
}

// Round 3
// 65.983 us; speedup vs baseline: 1.0335x; 1.0005x over previous
//
#include <hip/hip_runtime.h>
#include <utility>

#define DEV __device__ __forceinline__

constexpr int NV = 16;
constexpr float STEP = 0.1f;
constexpr int MAX_ITER = 20;

// ---- compile-time for loop (DPP ctrl / register indices must be ICEs) ----
template <class F, int... Is>
DEV void sf_impl(F&& f, std::integer_sequence<int, Is...>) {
  (f(std::integral_constant<int, Is>{}), ...);
}
template <int N, class F>
DEV void static_for(F&& f) {
  sf_impl(f, std::make_integer_sequence<int, N>{});
}

// ---- broadcast lane Q within each quad via DPP quad_perm (pure VALU, no LDS) ----
// old operand = src (don't-care: all lanes written at masks 0xF + bound_ctrl),
// avoids the compiler materializing a v_mov 0 for `old`.
template <int Q>
DEV float qbcast(float v) {
  int iv = __float_as_int(v);
  int r = __builtin_amdgcn_update_dpp(iv, iv, Q * 0x55, 0xF, 0xF, true);
  return __int_as_float(r);
}

// v_rcp_f32 is ~1 ulp: plenty for a 0.1-damped Newton trajectory at 3e-2 tol.
DEV float rcp_fast(float x) { return __builtin_amdgcn_rcpf(x); }

// One quad (4 lanes) per batch row. Lane l owns global variable rows {4l..4l+3}.
// Everything register-resident with static indexing; all cross-lane = DPP quad bcast.
// waves_per_eu(2,2): occupancy is thread-limited to 2 waves/SIMD anyway, so let
// the allocator use up to 256 VGPRs -> Arow/Jm stay resident (no per-iter remat).
__global__ __attribute__((amdgpu_flat_work_group_size(256, 256),
                          amdgpu_waves_per_eu(2, 2)))
void newton16(const float* __restrict__ y0, const float* __restrict__ xin,
              const float* __restrict__ Ain, float* __restrict__ out, int B) {
  const int tid = blockIdx.x * blockDim.x + threadIdx.x;
  const int g = tid >> 2;  // batch row
  const int l = tid & 3;   // lane within quad
  if (g >= B) return;

  // A rows for my 4 variables: 64 VGPRs, loaded once (must STAY resident)
  float Arow[4][16];
#pragma unroll
  for (int m = 0; m < 4; ++m) {
    const float4* ap = reinterpret_cast<const float4*>(Ain + (4 * l + m) * NV);
#pragma unroll
    for (int t = 0; t < 4; ++t) {
      float4 a = ap[t];
      Arow[m][4 * t + 0] = a.x;
      Arow[m][4 * t + 1] = a.y;
      Arow[m][4 * t + 2] = a.z;
      Arow[m][4 * t + 3] = a.w;
    }
  }

  float y[4], x[4];
  {
    float4 t = *reinterpret_cast<const float4*>(y0 + g * NV + 4 * l);
    y[0] = t.x; y[1] = t.y; y[2] = t.z; y[3] = t.w;
    float4 u = *reinterpret_cast<const float4*>(xin + g * NV + 4 * l);
    x[0] = u.x; x[1] = u.y; x[2] = u.z; x[3] = u.w;
  }

  // eqf[q] = (l==q) ? 1 : 0 ; neqf = 1 - eqf  (hoisted mask constants)
  float eqf[4], neqf[4];
#pragma unroll
  for (int q = 0; q < 4; ++q) {
    eqf[q] = (l == q) ? 1.0f : 0.0f;
    neqf[q] = 1.0f - eqf[q];
  }

#pragma unroll 1  // keep body ~1k instrs: full unroll would thrash I-cache
  for (int it = 0; it < MAX_ITER; ++it) {
    // local trig (args O(1) rad -> hw v_sin/v_cos fine)
    float s[4], c[4];
#pragma unroll
    for (int m = 0; m < 4; ++m) {
      s[m] = __sinf(y[m]);
      c[m] = __cosf(y[m]);
    }

    // full sin/cos vectors via quad broadcast (32 DPP movs)
    float sf16[16], cf16[16];
    static_for<16>([&](auto JJ) {
      constexpr int j = JJ.value;
      sf16[j] = qbcast<(j >> 2)>(s[j & 3]);
      cf16[j] = qbcast<(j >> 2)>(c[j & 3]);
    });

    // b = -r = x - y^3 - A*sin(y)   (for my 4 rows)
    float b[4];
#pragma unroll
    for (int m = 0; m < 4; ++m) {
      float acc = x[m] - y[m] * y[m] * y[m];
#pragma unroll
      for (int j = 0; j < 16; ++j) acc = __builtin_fmaf(-Arow[m][j], sf16[j], acc);
      b[m] = acc;
    }

    // J rows: J[m][j] = A[m][j]*cos(y_j) + (4l+m==j)*3*y_m^2
    float Jm[4][16];
#pragma unroll
    for (int m = 0; m < 4; ++m) {
      float t3 = 3.0f * y[m] * y[m];
#pragma unroll
      for (int j = 0; j < 16; ++j) {
        float v = Arow[m][j] * cf16[j];
        if ((j & 3) == m) v = __builtin_fmaf(eqf[j >> 2], t3, v);  // static cond on (j,m)
        Jm[m][j] = v;
      }
    }

    // ---- unpivoted Gauss-Jordan, fully unrolled; pivot k owned by lane k>>2 slot k&3 ----
    float dg[4] = {1.0f, 1.0f, 1.0f, 1.0f};
    static_for<16>([&](auto KK) {
      constexpr int k = KK.value;
      constexpr int q = k >> 2, mk = k & 3;
      float pk = qbcast<q>(Jm[mk][k]);
      float bk = qbcast<q>(b[mk]);
      float inv = rcp_fast(pk);
      float f[4];
#pragma unroll
      for (int m = 0; m < 4; ++m) f[m] = Jm[m][k] * inv;
      f[mk] *= neqf[q];                  // owner lane keeps its pivot row
      dg[mk] = (l == q) ? pk : dg[mk];   // save my diagonal pivot
      static_for<16 - k - 1>([&](auto JJ) {
        constexpr int j = k + 1 + JJ.value;
        float rkj = qbcast<q>(Jm[mk][j]);
#pragma unroll
        for (int m = 0; m < 4; ++m) Jm[m][j] = __builtin_fmaf(-f[m], rkj, Jm[m][j]);
      });
#pragma unroll
      for (int m = 0; m < 4; ++m) b[m] = __builtin_fmaf(-f[m], bk, b[m]);
    });

    // delta = b / diag;  y += STEP*delta
#pragma unroll
    for (int m = 0; m < 4; ++m) {
      float d = b[m] * rcp_fast(dg[m]);
      y[m] = __builtin_fmaf(STEP, d, y[m]);
    }
  }

  float4 o;
  o.x = y[0]; o.y = y[1]; o.z = y[2]; o.w = y[3];
  *reinterpret_cast<float4*>(out + g * NV + 4 * l) = o;
}

extern "C" void kernel_launch(void* const* d_in, const int* in_sizes, int n_in,
                              void* d_out, int out_size, void* d_ws, size_t ws_size,
                              hipStream_t stream) {
  const float* y = (const float*)d_in[0];
  const float* x = (const float*)d_in[1];
  const float* A = (const float*)d_in[2];
  float* out = (float*)d_out;
  const int B = in_sizes[0] / NV;      // 32768
  const int threads = B * 4;           // one quad per batch row
  dim3 block(256);
  dim3 grid((threads + block.x - 1) / block.x);
  hipLaunchKernelGGL(newton16, grid, block, 0, stream, y, x, A, out, B);
}

// Round 4
// 60.416 us; speedup vs baseline: 1.1287x; 1.0921x over previous
//
#include <hip/hip_runtime.h>
#include <utility>

#define DEV __device__ __forceinline__

constexpr int NV = 16;
constexpr float STEP = 0.1f;
constexpr int MAX_ITER = 20;
constexpr int LDA = 20;  // padded LDS row stride (floats): 80 B -> only 2-way bank alias (free)

// ---- compile-time for loop (DPP ctrl / register indices must be ICEs) ----
template <class F, int... Is>
DEV void sf_impl(F&& f, std::integer_sequence<int, Is...>) {
  (f(std::integral_constant<int, Is>{}), ...);
}
template <int N, class F>
DEV void static_for(F&& f) {
  sf_impl(f, std::make_integer_sequence<int, N>{});
}

// ---- broadcast lane Q within each quad via DPP quad_perm (pure VALU, no LDS) ----
template <int Q>
DEV float qbcast(float v) {
  int iv = __float_as_int(v);
  int r = __builtin_amdgcn_update_dpp(iv, iv, Q * 0x55, 0xF, 0xF, true);
  return __int_as_float(r);
}

// v_rcp_f32 is ~1 ulp: plenty for a 0.1-damped Newton trajectory at 3e-2 tol.
DEV float rcp_fast(float x) { return __builtin_amdgcn_rcpf(x); }

// One quad (4 lanes) per batch row; lane l owns rows {4l..4l+3}.
//
// Key restructure vs R3:
//  * u-substitution: solve (A + diag(3y^2/cos(y))) u = b, then delta = u/cos.
//    -> no per-iter Jacobian multiply pass, no cos broadcasts.
//  * A is batch-invariant: staged once into LDS; per-iter ds_read_b128 both
//    initializes M and feeds the residual fma pass (no 64-reg Arow, no remat).
//  * per GJ step: rcp(pivot) computed locally BEFORE the DPP broadcast, so the
//    quarter-rate rcp overlaps the previous step's fma burst.
__global__ __attribute__((amdgpu_flat_work_group_size(256, 256),
                          amdgpu_waves_per_eu(2, 2)))
void newton16(const float* __restrict__ y0, const float* __restrict__ xin,
              const float* __restrict__ Ain, float* __restrict__ out, int B) {
  __shared__ float Alds[NV * LDA];
  {  // stage A (16x16) once per block, padded rows
    const int t = threadIdx.x;
    if (t < 64) {
      const int row = t >> 2, seg = t & 3;
      float4 a = *reinterpret_cast<const float4*>(Ain + row * NV + seg * 4);
      *reinterpret_cast<float4*>(&Alds[row * LDA + seg * 4]) = a;
    }
  }
  __syncthreads();  // all threads reach this (full blocks), guard comes after

  const int tid = blockIdx.x * blockDim.x + threadIdx.x;
  const int g = tid >> 2;  // batch row
  const int l = tid & 3;   // lane within quad
  if (g >= B) return;

  float y[4], x[4];
  {
    float4 t = *reinterpret_cast<const float4*>(y0 + g * NV + 4 * l);
    y[0] = t.x; y[1] = t.y; y[2] = t.z; y[3] = t.w;
    float4 u = *reinterpret_cast<const float4*>(xin + g * NV + 4 * l);
    x[0] = u.x; x[1] = u.y; x[2] = u.z; x[3] = u.w;
  }

  float eqf[4], neqf[4];
#pragma unroll
  for (int q = 0; q < 4; ++q) {
    eqf[q] = (l == q) ? 1.0f : 0.0f;
    neqf[q] = 1.0f - eqf[q];
  }

  const float* __restrict__ Arow0 = &Alds[(4 * l) * LDA];

#pragma unroll 1  // keep body ~1k instrs; full unroll would thrash I-cache
  for (int it = 0; it < MAX_ITER; ++it) {
    // trig + diagonal term t_m = 3*y^2/cos(y)  (args O(1) rad -> hw trig fine)
    float s4[4], rc[4], tdiag[4], y2[4];
#pragma unroll
    for (int m = 0; m < 4; ++m) {
      y2[m] = y[m] * y[m];
      s4[m] = __sinf(y[m]);
      float c = __cosf(y[m]);
      rc[m] = rcp_fast(c);
      tdiag[m] = 3.0f * y2[m] * rc[m];
    }

    // full sin vector via quad broadcast (16 DPP)
    float sf[16];
    static_for<16>([&](auto JJ) {
      constexpr int j = JJ.value;
      sf[j] = qbcast<(j >> 2)>(s4[j & 3]);
    });

    // fused pass: M rows <- A rows (LDS), residual b = x - y^3 - A*sin(y)
    float b[4], M[4][16];
#pragma unroll
    for (int m = 0; m < 4; ++m) b[m] = x[m] - y2[m] * y[m];
    static_for<4>([&](auto MM) {
      constexpr int m = MM.value;
      static_for<4>([&](auto TT) {
        constexpr int t = TT.value;
        float4 a4 = *reinterpret_cast<const float4*>(Arow0 + m * LDA + 4 * t);
        M[m][4 * t + 0] = a4.x; M[m][4 * t + 1] = a4.y;
        M[m][4 * t + 2] = a4.z; M[m][4 * t + 3] = a4.w;
        b[m] = __builtin_fmaf(-a4.x, sf[4 * t + 0], b[m]);
        b[m] = __builtin_fmaf(-a4.y, sf[4 * t + 1], b[m]);
        b[m] = __builtin_fmaf(-a4.z, sf[4 * t + 2], b[m]);
        b[m] = __builtin_fmaf(-a4.w, sf[4 * t + 3], b[m]);
      });
    });
    // diagonal add: row 4l+m's diagonal sits in column block t==l, slot m
    static_for<4>([&](auto MM) {
      constexpr int m = MM.value;
      static_for<4>([&](auto TT) {
        constexpr int t = TT.value;
        M[m][4 * t + m] = __builtin_fmaf(eqf[t], tdiag[m], M[m][4 * t + m]);
      });
    });

    // ---- unpivoted Gauss-Jordan on M (A + diag, diag-dominant) ----
    float dginv[4] = {1.0f, 1.0f, 1.0f, 1.0f};
    static_for<16>([&](auto KK) {
      constexpr int k = KK.value;
      constexpr int q = k >> 2, mk = k & 3;
      float invl = rcp_fast(M[mk][k]);  // local rcp BEFORE bcast (overlaps prev burst)
      float inv = qbcast<q>(invl);
      float bk = qbcast<q>(b[mk]);
      float f[4];
#pragma unroll
      for (int m = 0; m < 4; ++m) f[m] = M[m][k] * inv;
      f[mk] *= neqf[q];                      // owner lane keeps its pivot row
      dginv[mk] = (l == q) ? inv : dginv[mk];  // capture own pivot inverse
      static_for<16 - k - 1>([&](auto JJ) {
        constexpr int j = k + 1 + JJ.value;
        float rkj = qbcast<q>(M[mk][j]);
#pragma unroll
        for (int m = 0; m < 4; ++m) M[m][j] = __builtin_fmaf(-f[m], rkj, M[m][j]);
      });
#pragma unroll
      for (int m = 0; m < 4; ++m) b[m] = __builtin_fmaf(-f[m], bk, b[m]);
    });

    // u = b*dginv ; delta = u/cos ; y += STEP*delta
#pragma unroll
    for (int m = 0; m < 4; ++m) {
      float u = b[m] * dginv[m];
      y[m] = __builtin_fmaf(STEP, u * rc[m], y[m]);
    }
  }

  float4 o;
  o.x = y[0]; o.y = y[1]; o.z = y[2]; o.w = y[3];
  *reinterpret_cast<float4*>(out + g * NV + 4 * l) = o;
}

extern "C" void kernel_launch(void* const* d_in, const int* in_sizes, int n_in,
                              void* d_out, int out_size, void* d_ws, size_t ws_size,
                              hipStream_t stream) {
  const float* y = (const float*)d_in[0];
  const float* x = (const float*)d_in[1];
  const float* A = (const float*)d_in[2];
  float* out = (float*)d_out;
  const int B = in_sizes[0] / NV;      // 32768
  const int threads = B * 4;           // one quad per batch row
  dim3 block(256);
  dim3 grid((threads + block.x - 1) / block.x);
  hipLaunchKernelGGL(newton16, grid, block, 0, stream, y, x, A, out, B);
}